// Round 11
// baseline (182.192 us; speedup 1.0000x reference)
//
#include <hip/hip_runtime.h>
#include <hip/hip_bf16.h>

// Problem constants
#define B_      8
#define N_      1024
#define DIM_    512
#define H_      8
#define DH_     64
#define INNER_  512
#define SCALE_  0.125f
#define LOG2E_  1.4426950408889634f

typedef __attribute__((ext_vector_type(8))) __bf16         bf16x8;
typedef __attribute__((ext_vector_type(8))) unsigned short ushort8;
typedef __attribute__((ext_vector_type(4))) float          f32x4;

union FragCast { ushort8 u; bf16x8 b; };
union FragU32  { unsigned int u[4]; bf16x8 b; };

__device__ inline bf16x8 ld_frag(const unsigned short* p) {
    FragCast f; f.u = *(const ushort8*)p; return f.b;
}

__device__ inline f32x4 mfma16(bf16x8 a, bf16x8 b, f32x4 c) {
    return __builtin_amdgcn_mfma_f32_16x16x32_bf16(a, b, c, 0, 0, 0);
}

__device__ inline float fexp2(float x) { return __builtin_amdgcn_exp2f(x); }

// round-to-nearest-even float -> bf16 bits
__device__ inline unsigned short f2bf(float x) {
    unsigned int u = __float_as_uint(x);
    unsigned int lsb = (u >> 16) & 1u;
    u += 0x7fffu + lsb;
    return (unsigned short)(u >> 16);
}

// truncating pack: (bf16(hi) << 16) | bf16(lo), one v_perm
__device__ inline unsigned int pack_bf2(float hi, float lo) {
    return __builtin_amdgcn_perm(__float_as_uint(hi), __float_as_uint(lo), 0x07060302u);
}

// async global->LDS, 16 bytes per lane (m97 pattern)
__device__ inline void gl_lds(const unsigned short* g, unsigned short* l) {
    __builtin_amdgcn_global_load_lds(
        (const __attribute__((address_space(1))) unsigned int*)g,
        (__attribute__((address_space(3))) unsigned int*)l, 16, 0, 0);
}

// raw barrier with compile-time memory fences (keeps gl_lds/ds_read on their
// side of the barrier without emitting a vmcnt(0) drain like __syncthreads)
#define BARF() do { asm volatile("" ::: "memory"); \
                    __builtin_amdgcn_s_barrier();  \
                    asm volatile("" ::: "memory"); } while (0)
#define WAITV(n) asm volatile("s_waitcnt vmcnt(" #n ")" ::: "memory")

// keep a bf16x8 fragment live via 4 scalar u32 asm operands
#define KEEP8(x) do { FragU32 _k; _k.b = (x); \
    asm volatile("" :: "v"(_k.u[0]), "v"(_k.u[1]), "v"(_k.u[2]), "v"(_k.u[3])); } while (0)

// ---------------------------------------------------------------------------
// K0: fp32 -> bf16 for the QKV GEMM's inputs ONLY (x, wqkv). The lidar /
// wout / wmerge conversions ride along in K1's grid (they are not needed
// until k_flash / k_gemm_out, so they overlap with the GEMM).
// ---------------------------------------------------------------------------
__global__ __launch_bounds__(256) void k_convert(
    const float* __restrict__ x, const float* __restrict__ wqkv,
    unsigned short* __restrict__ x_bf, unsigned short* __restrict__ wqkv_bf)
{
    const int bx = blockIdx.x, tid = threadIdx.x;
    const float* src; unsigned short* dst; long base;
    if (bx < 1024) { src = x;    dst = x_bf;    base = (long)bx * 1024; }
    else           { src = wqkv; dst = wqkv_bf; base = (long)(bx - 1024) * 1024; }
    for (int k = 0; k < 4; k++) {
        long j = base + k * 256 + tid;
        float4 v = ((const float4*)src)[j];
        ushort4 o;
        o.x = f2bf(v.x); o.y = f2bf(v.y); o.z = f2bf(v.z); o.w = f2bf(v.w);
        ((ushort4*)dst)[j] = o;
    }
}

// ---------------------------------------------------------------------------
// K1: QKV GEMM (blocks 0..767) + grid-fused conversions (blocks 768..1856):
//   768..1791  : lidar -> lid_bf (bf16) + out_lidar (fp32 copy)
//   1792..1855 : wout -> wout_bf
//   1856       : wmerge -> wm_bf
// The conversion blocks are memory-bound and fill scheduler slack under the
// compute-bound GEMM; they early-return before any barrier.
// GEMM: C = A * B^T, 128x128 tile, BK=64, XOR-swizzled async staging.
// ---------------------------------------------------------------------------
__global__ __launch_bounds__(256) void k_gemm_qkv(
    const unsigned short* __restrict__ A, const unsigned short* __restrict__ Bm,
    unsigned short* __restrict__ C, unsigned short* __restrict__ vt,
    const float* __restrict__ lidar, float* __restrict__ out_lidar,
    unsigned short* __restrict__ lid_bf,
    const float* __restrict__ wout, unsigned short* __restrict__ wout_bf,
    const float* __restrict__ wmerge, unsigned short* __restrict__ wm_bf)
{
    __shared__ unsigned short sMem[128 * 136];   // sA|sB in main loop; sT in V epilogue
    const int bx = blockIdx.x, tid = threadIdx.x;

    if (bx >= 768) {
        // ---- fused conversion blocks ----
        const float* src; unsigned short* dst; bool isLid = false; long base;
        if (bx < 1792)      { src = lidar;  dst = lid_bf;  base = (long)(bx - 768) * 1024; isLid = true; }
        else if (bx < 1856) { src = wout;   dst = wout_bf; base = (long)(bx - 1792) * 1024; }
        else                { src = wmerge; dst = wm_bf;   base = 0; }
        for (int k = 0; k < 4; k++) {
            long j = base + k * 256 + tid;
            float4 v = ((const float4*)src)[j];
            ushort4 o;
            o.x = f2bf(v.x); o.y = f2bf(v.y); o.z = f2bf(v.z); o.w = f2bf(v.w);
            ((ushort4*)dst)[j] = o;
            if (isLid) ((float4*)out_lidar)[j] = v;
        }
        return;
    }

    // ---- GEMM blocks ----
    unsigned short* sA = sMem;                   // 128*64
    unsigned short* sB = sMem + 128 * 64;        // 128*64
    const int K = DIM_, Nd = 3 * INNER_;
    const int lane = tid & 63, wave = tid >> 6;
    const int q = lane >> 4, l15 = lane & 15, l7 = l15 & 7;
    const int xq0 = (q ^ l7) << 3, xq4 = ((q + 4) ^ l7) << 3;
    const int m0 = (bx & 63) * 128, n0 = (bx >> 6) * 128;
    const int wm = (wave >> 1) * 64, wn = (wave & 1) * 64;
    f32x4 acc[4][4] = {};

    for (int k0 = 0; k0 < K; k0 += 64) {
        __syncthreads();
        for (int i = 0; i < 4; i++) {
            int c = i * 256 + tid;
            int row = c >> 3;
            int gcol = ((c & 7) ^ (row & 7)) << 3;
            gl_lds(&A[(long)(m0 + row) * K + k0 + gcol], &sA[c * 8]);
            gl_lds(&Bm[(long)(n0 + row) * K + k0 + gcol], &sB[c * 8]);
        }
        __syncthreads();
        for (int kk = 0; kk < 2; kk++) {
            const int xx = kk ? xq4 : xq0;
            bf16x8 af[4], bfr[4];
            for (int i = 0; i < 4; i++)
                af[i]  = ld_frag(&sA[(wm + i * 16 + l15) * 64 + xx]);
            for (int i = 0; i < 4; i++)
                bfr[i] = ld_frag(&sB[(wn + i * 16 + l15) * 64 + xx]);
            for (int mi = 0; mi < 4; mi++)
                for (int ni = 0; ni < 4; ni++)
                    acc[mi][ni] = mfma16(af[mi], bfr[ni], acc[mi][ni]);
        }
    }
    if (n0 < 1024) {
        for (int mi = 0; mi < 4; mi++)
            for (int ni = 0; ni < 4; ni++)
                for (int r = 0; r < 4; r++) {
                    int row = m0 + wm + mi * 16 + q * 4 + r;
                    int col = n0 + wn + ni * 16 + l15;
                    C[(long)row * Nd + col] = f2bf(acc[mi][ni][r]);
                }
    } else {
        // ---- V epilogue: acc -> LDS sT[f][tok] (stride 136) -> coalesced vt ----
        __syncthreads();   // all waves done reading sA/sB
        for (int mi = 0; mi < 4; mi++) {
            int t0 = wm + mi * 16 + q * 4;
            for (int ni = 0; ni < 4; ni++) {
                int f = wn + ni * 16 + l15;
                ushort4 o4;
                o4.x = f2bf(acc[mi][ni][0]); o4.y = f2bf(acc[mi][ni][1]);
                o4.z = f2bf(acc[mi][ni][2]); o4.w = f2bf(acc[mi][ni][3]);
                *(ushort4*)&sMem[f * 136 + t0] = o4;   // 8B store, 2-way alias = free
            }
        }
        __syncthreads();
        const long fb = (long)(n0 - 1024) * (B_ * N_) + m0;
        for (int i = 0; i < 8; i++) {
            int g = i * 256 + tid;              // 128 f x 16 groups
            int f = g >> 4, grp = g & 15;
            int base = (grp >> 2) * 32 + (grp & 3) * 4;
            ushort4 a4 = *(const ushort4*)&sMem[f * 136 + base];
            ushort4 b4 = *(const ushort4*)&sMem[f * 136 + base + 16];
            ushort8 o8 = {a4.x, a4.y, a4.z, a4.w, b4.x, b4.y, b4.z, b4.w};
            *(ushort8*)&vt[fb + (long)f * (B_ * N_) + grp * 8] = o8;
        }
    }
}

// ---------------------------------------------------------------------------
// K3: out GEMM (fp32 out + bias), 128x64 tile, BK=64, swizzled async staging.
// ---------------------------------------------------------------------------
__global__ __launch_bounds__(256) void k_gemm_out(
    const unsigned short* __restrict__ A, const unsigned short* __restrict__ Bm,
    const float* __restrict__ bias, float* __restrict__ C, int M, int Nd, int K)
{
    __shared__ unsigned short sA[128 * 64];
    __shared__ unsigned short sB[64 * 64];
    const int tid  = threadIdx.x;
    const int lane = tid & 63, wave = tid >> 6;
    const int q = lane >> 4, l15 = lane & 15, l7 = l15 & 7;
    const int xq0 = (q ^ l7) << 3, xq4 = ((q + 4) ^ l7) << 3;
    const int m0 = blockIdx.x * 128, n0 = blockIdx.y * 64;
    const int wm = (wave >> 1) * 64, wn = (wave & 1) * 32;
    f32x4 acc[4][2] = {};

    for (int k0 = 0; k0 < K; k0 += 64) {
        __syncthreads();
        for (int i = 0; i < 4; i++) {
            int c = i * 256 + tid;
            int row = c >> 3;
            int gcol = ((c & 7) ^ (row & 7)) << 3;
            gl_lds(&A[(long)(m0 + row) * K + k0 + gcol], &sA[c * 8]);
            if (i < 2)
                gl_lds(&Bm[(long)(n0 + row) * K + k0 + gcol], &sB[c * 8]);
        }
        __syncthreads();
        for (int kk = 0; kk < 2; kk++) {
            const int xx = kk ? xq4 : xq0;
            bf16x8 af[4], bfr[2];
            for (int i = 0; i < 4; i++)
                af[i]  = ld_frag(&sA[(wm + i * 16 + l15) * 64 + xx]);
            for (int i = 0; i < 2; i++)
                bfr[i] = ld_frag(&sB[(wn + i * 16 + l15) * 64 + xx]);
            for (int mi = 0; mi < 4; mi++)
                for (int ni = 0; ni < 2; ni++)
                    acc[mi][ni] = mfma16(af[mi], bfr[ni], acc[mi][ni]);
        }
    }
    for (int mi = 0; mi < 4; mi++)
        for (int ni = 0; ni < 2; ni++)
            for (int r = 0; r < 4; r++) {
                int row = m0 + wm + mi * 16 + q * 4 + r;
                int col = n0 + wn + ni * 16 + l15;
                C[(long)row * Nd + col] = acc[mi][ni][r] + bias[col];
            }
}

// ---------------------------------------------------------------------------
// K2 compute bodies. Buffer bases are template constants: every ds_read is
// per-lane base + immediate offset (no runtime buffer adds).
// ---------------------------------------------------------------------------

// sweep-1: 128 lidar rows at base SB
template <int SB>
__device__ __forceinline__ void comp1(const unsigned short* smem, int a0, int a4,
                                      const bf16x8* lfq, float sc, float& rsl)
{
#pragma unroll
    for (int ns = 0; ns < 8; ns++) {
        f32x4 cv = {0.f, 0.f, 0.f, 0.f};
        cv = mfma16(ld_frag(&smem[SB + ns * 1024 + a0]), lfq[0], cv);
        cv = mfma16(ld_frag(&smem[SB + ns * 1024 + a4]), lfq[1], cv);
#pragma unroll
        for (int r = 0; r < 4; r++) rsl += fexp2(cv[r] * sc);
    }
}

// sweep-2: one 64-token tile at base KB; L at KB+4096, V^T at KB+8192.
template <int KB>
__device__ __forceinline__ void comp2(const unsigned short* smem, int a0, int a4,
                                      const bf16x8* qf, const bf16x8* lfq,
                                      float k0c, float k2c, float k1, float sc,
                                      float& rs, f32x4* o)
{
#pragma unroll
    for (int ns2 = 0; ns2 < 2; ns2++) {
        FragU32 fa;
#pragma unroll
        for (int h2 = 0; h2 < 2; h2++) {
            const int ns = ns2 * 2 + h2;
            f32x4 a = {0.f, 0.f, 0.f, 0.f};
            a = mfma16(ld_frag(&smem[KB + ns * 1024 + a0]), qf[0], a);
            a = mfma16(ld_frag(&smem[KB + ns * 1024 + a4]), qf[1], a);
            f32x4 cv = {0.f, 0.f, 0.f, 0.f};
            cv = mfma16(ld_frag(&smem[KB + 4096 + ns * 1024 + a0]), lfq[0], cv);
            cv = mfma16(ld_frag(&smem[KB + 4096 + ns * 1024 + a4]), lfq[1], cv);
            float pv[4];
#pragma unroll
            for (int r = 0; r < 4; r++) {
                float els = fexp2(cv[r] * sc);
                float t = fmaf(k0c, a[r], k2c);
                t = fmaf(k1, els, t);
                pv[r] = fexp2(t);
                rs += pv[r];
            }
            fa.u[h2 * 2 + 0] = pack_bf2(pv[1], pv[0]);
            fa.u[h2 * 2 + 1] = pack_bf2(pv[3], pv[2]);
        }
        const int av = ns2 ? a4 : a0;
#pragma unroll
        for (int dt = 0; dt < 4; dt++)
            o[dt] = mfma16(fa.b, ld_frag(&smem[KB + 8192 + dt * 1024 + av]), o[dt]);
    }
}

// ---------------------------------------------------------------------------
// K2: fused flash attention, 512-thread blocks (8 waves), 128 query rows per
// block. 3-buffer LDS (72KB) with ONE barrier per tile (R10 structure):
// {WAITV(counted); BARF; compute(t); issue(t+2)} — issue targets buf[(t-1)%3]
// whose readers finished before this barrier. All bases template constants.
// ---------------------------------------------------------------------------
__global__ __launch_bounds__(512) void k_flash(
    const unsigned short* __restrict__ qkv_bf, const unsigned short* __restrict__ lid_bf,
    const unsigned short* __restrict__ vt,
    const unsigned short* __restrict__ wm_bf, const float* __restrict__ b_merge,
    const float* __restrict__ conv_w, const float* __restrict__ conv_b,
    unsigned short* __restrict__ tmp_bf)
{
    __shared__ unsigned short smem[36864];   // 72KB: sweep2 bufs at 0/12288/24576
    __shared__ float sRS[8][16];

    const int tid = threadIdx.x, lane = tid & 63, wave = tid >> 6;   // wave 0..7
    const int q = lane >> 4, l15 = lane & 15, l7 = l15 & 7;
    const int xq0 = (q ^ l7) << 3, xq4 = ((q + 4) ^ l7) << 3;
    const int a0 = l15 * 64 + xq0, a4 = l15 * 64 + xq4;
    const int bh = blockIdx.x, ipair = blockIdx.y;   // x=bh for XCD locality
    const int b = bh >> 3, h = bh & 7;
    const int i0w = ipair * 128 + wave * 16;
    const long rowB = (long)b * N_;
    const int colh = h * DH_;
    const float k0c = conv_w[0] * SCALE_ * LOG2E_;
    const float k2c = conv_b[0] * LOG2E_;
    const float c1L = conv_w[1] * LOG2E_;
    const float sc = SCALE_ * LOG2E_;

    // per-thread staging chunk base (16B per thread per 8KB sub-buffer)
    const int srow = tid >> 3;                                // 0..63
    const int sgc  = ((tid & 7) ^ (srow & 7)) << 3;
    unsigned short* sd = &smem[tid * 8];
    const unsigned short* gK = &qkv_bf[(rowB + srow) * 1536 + 512 + colh + sgc];
    const unsigned short* gL = &lid_bf[(rowB + srow) * INNER_ + colh + sgc];
    const unsigned short* gV = &vt[(long)(colh + srow) * (B_ * N_) + rowB + sgc];
    const unsigned short* gL1a = &lid_bf[(rowB + srow) * INNER_ + colh + sgc];
    const unsigned short* gL1b = &lid_bf[(rowB + 64 + srow) * INNER_ + colh + sgc];

    // Q / lid query fragments (B-operand: row i = l15, contiguous d)
    bf16x8 qf[2], lfq[2];
#pragma unroll
    for (int ks = 0; ks < 2; ks++) {
        qf[ks]  = ld_frag(&qkv_bf[(rowB + i0w + l15) * 1536 + colh + ks * 32 + q * 8]);
        lfq[ks] = ld_frag(&lid_bf[(rowB + i0w + l15) * INNER_ + colh + ks * 32 + q * 8]);
    }
    // force materialization so the compiler's waitcnt for these loads lands
    // HERE, not as a vmcnt(0) drain inside the pipelined loops
    KEEP8(qf[0]); KEEP8(qf[1]); KEEP8(lfq[0]); KEEP8(lfq[1]);
    WAITV(0);

    // ISS1(off): stage one 128-row lidar tile (16KB = 2 gl_lds) at ushort off
#define ISS1(off) do { gl_lds(gL1a, sd + (off)); gl_lds(gL1b, sd + (off) + 4096); \
                       gL1a += 128 * INNER_; gL1b += 128 * INNER_; } while (0)
    // ISS2(off): stage one 64-token K|L|V tile (24KB = 3 gl_lds) at ushort off
#define ISS2(off) do { gl_lds(gK, sd + (off)); gl_lds(gL, sd + (off) + 4096); \
                       gl_lds(gV, sd + (off) + 8192); \
                       gK += 64 * 1536; gL += 64 * INNER_; gV += 64; } while (0)

    // ---- sweep 1: lidar softmax denominator (8 tiles x 128 rows, 16KB each,
    //      3 buffers at ushort offsets 0 / 8192 / 16384; one barrier/tile) ----
    float rsl = 0.f;
    ISS1(0); ISS1(8192);                  // t0 -> buf0, t1 -> buf1
#pragma unroll
    for (int t = 0; t < 8; t++) {
        if (t < 7) { WAITV(2); } else { WAITV(0); }
        BARF();
        __builtin_amdgcn_s_setprio(1);
        if      (t % 3 == 0) comp1<0>    (smem, a0, a4, lfq, sc, rsl);
        else if (t % 3 == 1) comp1<8192> (smem, a0, a4, lfq, sc, rsl);
        else                 comp1<16384>(smem, a0, a4, lfq, sc, rsl);
        __builtin_amdgcn_s_setprio(0);
        if (t + 2 < 8) {
            if      ((t + 2) % 3 == 0) ISS1(0);
            else if ((t + 2) % 3 == 1) ISS1(8192);
            else                       ISS1(16384);
        }
    }

    // transition: all waves done reading sweep-1 buffers before sweep-2
    // staging overwrites the region
    BARF();
    ISS2(0); ISS2(12288);                 // t0 -> buf0, t1 -> buf1
    rsl += __shfl_xor(rsl, 16);           // reduce hides under the loads
    rsl += __shfl_xor(rsl, 32);
    const float k1 = c1L / rsl;
    float rs = 0.f;
    f32x4 o[4] = {};   // o[dt]: lane holds O[i = q*4+r][d = dt*16 + l15]

    // ---- sweep 2: blended flash (16 tiles x 64 tokens, 24KB each,
    //      3 buffers at ushort offsets 0 / 12288 / 24576; one barrier/tile) ----
#pragma unroll
    for (int t = 0; t < 16; t++) {
        if (t < 15) { WAITV(3); } else { WAITV(0); }
        BARF();
        __builtin_amdgcn_s_setprio(1);
        if      (t % 3 == 0) comp2<0>    (smem, a0, a4, qf, lfq, k0c, k2c, k1, sc, rs, o);
        else if (t % 3 == 1) comp2<12288>(smem, a0, a4, qf, lfq, k0c, k2c, k1, sc, rs, o);
        else                 comp2<24576>(smem, a0, a4, qf, lfq, k0c, k2c, k1, sc, rs, o);
        __builtin_amdgcn_s_setprio(0);
        if (t + 2 < 16) {
            if      ((t + 2) % 3 == 0) ISS2(0);
            else if ((t + 2) % 3 == 1) ISS2(12288);
            else                       ISS2(24576);
        }
    }
#undef ISS1
#undef ISS2
    BARF();   // all waves done reading tile buffers -> pO overlay safe

    // ---- epilogue: normalize + fused per-head merge ----
    rs += __shfl_xor(rs, 16);
    rs += __shfl_xor(rs, 32);
    if (q == 0) sRS[wave][l15] = rs;          // wave-private, in-order
    float invr[4];
    for (int r = 0; r < 4; r++) invr[r] = 1.f / sRS[wave][q * 4 + r];

    unsigned short* pO = &smem[wave * 16 * 72];
#pragma unroll
    for (int dt = 0; dt < 4; dt++)
        for (int r = 0; r < 4; r++)
            pO[(q * 4 + r) * 72 + dt * 16 + l15] = f2bf(o[dt][r] * invr[r]);

    f32x4 mo[4] = {};
#pragma unroll
    for (int ks = 0; ks < 2; ks++) {
        bf16x8 af = ld_frag(&pO[l15 * 72 + ks * 32 + q * 8]);
#pragma unroll
        for (int ns = 0; ns < 4; ns++) {
            bf16x8 wf = ld_frag(&wm_bf[(ns * 16 + l15) * 64 + ks * 32 + q * 8]);
            mo[ns] = mfma16(af, wf, mo[ns]);
        }
    }
#pragma unroll
    for (int ns = 0; ns < 4; ns++) {
        float bm = b_merge[ns * 16 + l15];
        for (int r = 0; r < 4; r++) {
            long row = rowB + i0w + q * 4 + r;
            tmp_bf[row * INNER_ + colh + ns * 16 + l15] = f2bf(mo[ns][r] + bm);
        }
    }
}

// ---------------------------------------------------------------------------
extern "C" void kernel_launch(void* const* d_in, const int* in_sizes, int n_in,
                              void* d_out, int out_size, void* d_ws, size_t ws_size,
                              hipStream_t stream) {
    const float* x       = (const float*)d_in[0];
    const float* lidar   = (const float*)d_in[1];
    const float* w_qkv   = (const float*)d_in[2];
    const float* w_merge = (const float*)d_in[3];
    const float* b_merge = (const float*)d_in[4];
    const float* w_out   = (const float*)d_in[5];
    const float* b_out   = (const float*)d_in[6];
    const float* conv_w  = (const float*)d_in[7];
    const float* conv_b  = (const float*)d_in[8];

    float* out0      = (float*)d_out;                      // [B,N,DIM]
    float* out_lidar = out0 + (long)B_ * N_ * INNER_;      // [B,N,INNER]

    size_t off = 0;
    auto carve = [&](size_t bytes) {
        void* p = (char*)d_ws + off;
        off += (bytes + 255) & ~(size_t)255;
        return p;
    };
    unsigned short* qkv_bf  = (unsigned short*)carve((size_t)B_ * N_ * 3 * INNER_ * 2);
    unsigned short* lid_bf  = (unsigned short*)carve((size_t)B_ * N_ * INNER_ * 2);
    unsigned short* x_bf    = (unsigned short*)carve((size_t)B_ * N_ * DIM_ * 2);
    unsigned short* wqkv_bf = (unsigned short*)carve((size_t)3 * INNER_ * DIM_ * 2);
    unsigned short* wout_bf = (unsigned short*)carve((size_t)DIM_ * INNER_ * 2);
    unsigned short* wm_bf   = (unsigned short*)carve((size_t)DH_ * DH_ * 2);
    unsigned short* tmp_bf  = (unsigned short*)carve((size_t)B_ * N_ * INNER_ * 2);
    unsigned short* vt_bf   = (unsigned short*)carve((size_t)INNER_ * B_ * N_ * 2);

    // K0: only the GEMM's inputs (x 1024 blocks + wqkv 192 blocks)
    k_convert<<<1216, 256, 0, stream>>>(x, w_qkv, x_bf, wqkv_bf);

    // K1: GEMM (768) + lidar convert (1024) + wout (64) + wmerge (1)
    k_gemm_qkv<<<1857, 256, 0, stream>>>(
        x_bf, wqkv_bf, qkv_bf, vt_bf,
        lidar, out_lidar, lid_bf,
        w_out, wout_bf, w_merge, wm_bf);

    k_flash<<<dim3(64, 8), 512, 0, stream>>>(
        qkv_bf, lid_bf, vt_bf, wm_bf, b_merge, conv_w, conv_b, tmp_bf);

    k_gemm_out<<<dim3(64, 8), 256, 0, stream>>>(
        tmp_bf, wout_bf, b_out, out0, B_ * N_, DIM_, INNER_);
}

// Round 12
// 175.097 us; speedup vs baseline: 1.0405x; 1.0405x over previous
//
#include <hip/hip_runtime.h>
#include <hip/hip_bf16.h>

// Problem constants
#define B_      8
#define N_      1024
#define DIM_    512
#define H_      8
#define DH_     64
#define INNER_  512
#define SCALE_  0.125f
#define LOG2E_  1.4426950408889634f

typedef __attribute__((ext_vector_type(8))) __bf16         bf16x8;
typedef __attribute__((ext_vector_type(8))) unsigned short ushort8;
typedef __attribute__((ext_vector_type(4))) float          f32x4;

union FragCast { ushort8 u; bf16x8 b; };
union FragU32  { unsigned int u[4]; bf16x8 b; };

__device__ inline bf16x8 ld_frag(const unsigned short* p) {
    FragCast f; f.u = *(const ushort8*)p; return f.b;
}

__device__ inline f32x4 mfma16(bf16x8 a, bf16x8 b, f32x4 c) {
    return __builtin_amdgcn_mfma_f32_16x16x32_bf16(a, b, c, 0, 0, 0);
}

__device__ inline float fexp2(float x) { return __builtin_amdgcn_exp2f(x); }

// round-to-nearest-even float -> bf16 bits
__device__ inline unsigned short f2bf(float x) {
    unsigned int u = __float_as_uint(x);
    unsigned int lsb = (u >> 16) & 1u;
    u += 0x7fffu + lsb;
    return (unsigned short)(u >> 16);
}

// truncating pack: (bf16(hi) << 16) | bf16(lo), one v_perm
__device__ inline unsigned int pack_bf2(float hi, float lo) {
    return __builtin_amdgcn_perm(__float_as_uint(hi), __float_as_uint(lo), 0x07060302u);
}

// async global->LDS, 16 bytes per lane (m97 pattern)
__device__ inline void gl_lds(const unsigned short* g, unsigned short* l) {
    __builtin_amdgcn_global_load_lds(
        (const __attribute__((address_space(1))) unsigned int*)g,
        (__attribute__((address_space(3))) unsigned int*)l, 16, 0, 0);
}

// raw barrier with compile-time memory fences (keeps gl_lds/ds_read on their
// side of the barrier without emitting a vmcnt(0) drain like __syncthreads)
#define BARF() do { asm volatile("" ::: "memory"); \
                    __builtin_amdgcn_s_barrier();  \
                    asm volatile("" ::: "memory"); } while (0)
#define WAITV(n) asm volatile("s_waitcnt vmcnt(" #n ")" ::: "memory")

// keep a bf16x8 fragment live via 4 scalar u32 asm operands
#define KEEP8(x) do { FragU32 _k; _k.b = (x); \
    asm volatile("" :: "v"(_k.u[0]), "v"(_k.u[1]), "v"(_k.u[2]), "v"(_k.u[3])); } while (0)

// ---------------------------------------------------------------------------
// K0: fp32 -> bf16 conversions, block-uniform region dispatch (R10 config).
// ---------------------------------------------------------------------------
__global__ __launch_bounds__(256) void k_convert(
    const float* __restrict__ x, const float* __restrict__ lidar,
    const float* __restrict__ wqkv, const float* __restrict__ wmerge,
    const float* __restrict__ wout,
    unsigned short* __restrict__ x_bf, unsigned short* __restrict__ lid_bf,
    float* __restrict__ out_lidar,
    unsigned short* __restrict__ wqkv_bf, unsigned short* __restrict__ wm_bf,
    unsigned short* __restrict__ wout_bf)
{
    const int bx = blockIdx.x, tid = threadIdx.x;
    const float* src; unsigned short* dst; bool isLid = false; long base;
    if (bx < 1024)      { src = x;      dst = x_bf;    base = (long)bx * 1024; }
    else if (bx < 2048) { src = lidar;  dst = lid_bf;  base = (long)(bx - 1024) * 1024; isLid = true; }
    else if (bx < 2240) { src = wqkv;   dst = wqkv_bf; base = (long)(bx - 2048) * 1024; }
    else if (bx < 2304) { src = wout;   dst = wout_bf; base = (long)(bx - 2240) * 1024; }
    else                { src = wmerge; dst = wm_bf;   base = 0; }
    for (int k = 0; k < 4; k++) {
        long j = base + k * 256 + tid;
        float4 v = ((const float4*)src)[j];
        ushort4 o;
        o.x = f2bf(v.x); o.y = f2bf(v.y); o.z = f2bf(v.z); o.w = f2bf(v.w);
        ((ushort4*)dst)[j] = o;
        if (isLid) ((float4*)out_lidar)[j] = v;
    }
}

// ---------------------------------------------------------------------------
// GEMM K-step compute: 128x64 tile, acc[4][2], fragments from buffer base KB
// (A at KB, B at KB+8192). Template-const base -> base+imm ds_reads.
// ---------------------------------------------------------------------------
template <int KB>
__device__ __forceinline__ void gemm_step(const unsigned short* smem,
                                          int wm, int wn, int l15,
                                          int xq0, int xq4, f32x4 acc[4][2])
{
#pragma unroll
    for (int kk = 0; kk < 2; kk++) {
        const int xx = kk ? xq4 : xq0;
        bf16x8 af[4], bfr[2];
#pragma unroll
        for (int i = 0; i < 4; i++)
            af[i]  = ld_frag(&smem[KB + (wm + i * 16 + l15) * 64 + xx]);
#pragma unroll
        for (int i = 0; i < 2; i++)
            bfr[i] = ld_frag(&smem[KB + 8192 + (wn + i * 16 + l15) * 64 + xx]);
#pragma unroll
        for (int mi = 0; mi < 4; mi++)
#pragma unroll
            for (int ni = 0; ni < 2; ni++)
                acc[mi][ni] = mfma16(af[mi], bfr[ni], acc[mi][ni]);
    }
}

// ---------------------------------------------------------------------------
// K1: QKV GEMM, C = A * B^T, 128x64 tile, BK=64, K=512 (8 steps).
// R10 schedule: 3-buffer LDS (3 x 24KB = 72KB), ONE barrier per K-step,
// counted vmcnt (WAITV(6) steady; drain only at tail), issue t+2 after
// compute(t). Q,K thirds -> qkv_bf rows; V third -> vt via LDS transpose.
// ---------------------------------------------------------------------------
__global__ __launch_bounds__(256) void k_gemm_qkv(
    const unsigned short* __restrict__ A, const unsigned short* __restrict__ Bm,
    unsigned short* __restrict__ C, unsigned short* __restrict__ vt)
{
    __shared__ unsigned short smem[36864];   // 72KB: bufs at 0 / 12288 / 24576
    const int tid  = threadIdx.x;
    const int lane = tid & 63, wave = tid >> 6;
    const int q = lane >> 4, l15 = lane & 15, l7 = l15 & 7;
    const int xq0 = (q ^ l7) << 3, xq4 = ((q + 4) ^ l7) << 3;
    const int m0 = blockIdx.x * 128, n0 = blockIdx.y * 64;
    const int wm = (wave >> 1) * 64, wn = (wave & 1) * 32;
    const int K = DIM_, Nd = 3 * INNER_;
    f32x4 acc[4][2] = {};

    // per-thread staging: rows r0+32i share (row&7) -> one gcol for all chunks
    const int r0  = tid >> 3;
    const int gc  = ((tid & 7) ^ (r0 & 7)) << 3;
    const unsigned short* gA0 = &A [(long)(m0 + r0      ) * K + gc];
    const unsigned short* gA1 = &A [(long)(m0 + r0 +  32) * K + gc];
    const unsigned short* gA2 = &A [(long)(m0 + r0 +  64) * K + gc];
    const unsigned short* gA3 = &A [(long)(m0 + r0 +  96) * K + gc];
    const unsigned short* gB0 = &Bm[(long)(n0 + r0      ) * K + gc];
    const unsigned short* gB1 = &Bm[(long)(n0 + r0 +  32) * K + gc];
    unsigned short* sd = &smem[tid * 8];

#define ISSG(off) do { \
    gl_lds(gA0, sd + (off));        gl_lds(gA1, sd + (off) + 2048);  \
    gl_lds(gA2, sd + (off) + 4096); gl_lds(gA3, sd + (off) + 6144);  \
    gl_lds(gB0, sd + (off) + 8192); gl_lds(gB1, sd + (off) + 10240); \
    gA0 += 64; gA1 += 64; gA2 += 64; gA3 += 64; gB0 += 64; gB1 += 64; } while (0)

    ISSG(0); ISSG(12288);                 // t0 -> buf0, t1 -> buf1
#pragma unroll
    for (int t = 0; t < 8; t++) {
        if (t < 7) { WAITV(6); } else { WAITV(0); }
        BARF();
        if      (t % 3 == 0) gemm_step<0>    (smem, wm, wn, l15, xq0, xq4, acc);
        else if (t % 3 == 1) gemm_step<12288>(smem, wm, wn, l15, xq0, xq4, acc);
        else                 gemm_step<24576>(smem, wm, wn, l15, xq0, xq4, acc);
        if (t + 2 < 8) {
            if      ((t + 2) % 3 == 0) ISSG(0);
            else if ((t + 2) % 3 == 1) ISSG(12288);
            else                       ISSG(24576);
        }
    }
#undef ISSG

    if (n0 < 1024) {
        for (int mi = 0; mi < 4; mi++)
            for (int ni = 0; ni < 2; ni++)
                for (int r = 0; r < 4; r++) {
                    int row = m0 + wm + mi * 16 + q * 4 + r;
                    int col = n0 + wn + ni * 16 + l15;
                    C[(long)row * Nd + col] = f2bf(acc[mi][ni][r]);
                }
    } else {
        // ---- V epilogue: acc -> LDS sT[f][tok] (64 x 136) -> coalesced vt ----
        BARF();   // all waves done reading tile buffers
        for (int mi = 0; mi < 4; mi++) {
            int t0 = wm + mi * 16 + q * 4;
            for (int ni = 0; ni < 2; ni++) {
                int f = wn + ni * 16 + l15;
                ushort4 o4;
                o4.x = f2bf(acc[mi][ni][0]); o4.y = f2bf(acc[mi][ni][1]);
                o4.z = f2bf(acc[mi][ni][2]); o4.w = f2bf(acc[mi][ni][3]);
                *(ushort4*)&smem[f * 136 + t0] = o4;   // 8B store, 2-way alias = free
            }
        }
        BARF();
        const long fb = (long)(n0 - 1024) * (B_ * N_) + m0;
        for (int i = 0; i < 4; i++) {
            int g = i * 256 + tid;              // 64 f x 16 groups
            int f = g >> 4, grp = g & 15;
            int base = (grp >> 2) * 32 + (grp & 3) * 4;
            ushort4 a4 = *(const ushort4*)&smem[f * 136 + base];
            ushort4 b4 = *(const ushort4*)&smem[f * 136 + base + 16];
            ushort8 o8 = {a4.x, a4.y, a4.z, a4.w, b4.x, b4.y, b4.z, b4.w};
            *(ushort8*)&vt[fb + (long)f * (B_ * N_) + grp * 8] = o8;
        }
    }
}

// ---------------------------------------------------------------------------
// K3: out GEMM (fp32 out + bias), 128x64 tile, K=512 — same R10 schedule.
// ---------------------------------------------------------------------------
__global__ __launch_bounds__(256) void k_gemm_out(
    const unsigned short* __restrict__ A, const unsigned short* __restrict__ Bm,
    const float* __restrict__ bias, float* __restrict__ C)
{
    __shared__ unsigned short smem[36864];   // 72KB: bufs at 0 / 12288 / 24576
    const int tid  = threadIdx.x;
    const int lane = tid & 63, wave = tid >> 6;
    const int q = lane >> 4, l15 = lane & 15, l7 = l15 & 7;
    const int xq0 = (q ^ l7) << 3, xq4 = ((q + 4) ^ l7) << 3;
    const int m0 = blockIdx.x * 128, n0 = blockIdx.y * 64;
    const int wm = (wave >> 1) * 64, wn = (wave & 1) * 32;
    const int K = INNER_, Nd = DIM_;
    f32x4 acc[4][2] = {};

    const int r0  = tid >> 3;
    const int gc  = ((tid & 7) ^ (r0 & 7)) << 3;
    const unsigned short* gA0 = &A [(long)(m0 + r0      ) * K + gc];
    const unsigned short* gA1 = &A [(long)(m0 + r0 +  32) * K + gc];
    const unsigned short* gA2 = &A [(long)(m0 + r0 +  64) * K + gc];
    const unsigned short* gA3 = &A [(long)(m0 + r0 +  96) * K + gc];
    const unsigned short* gB0 = &Bm[(long)(n0 + r0      ) * K + gc];
    const unsigned short* gB1 = &Bm[(long)(n0 + r0 +  32) * K + gc];
    unsigned short* sd = &smem[tid * 8];

#define ISSG(off) do { \
    gl_lds(gA0, sd + (off));        gl_lds(gA1, sd + (off) + 2048);  \
    gl_lds(gA2, sd + (off) + 4096); gl_lds(gA3, sd + (off) + 6144);  \
    gl_lds(gB0, sd + (off) + 8192); gl_lds(gB1, sd + (off) + 10240); \
    gA0 += 64; gA1 += 64; gA2 += 64; gA3 += 64; gB0 += 64; gB1 += 64; } while (0)

    ISSG(0); ISSG(12288);
#pragma unroll
    for (int t = 0; t < 8; t++) {
        if (t < 7) { WAITV(6); } else { WAITV(0); }
        BARF();
        if      (t % 3 == 0) gemm_step<0>    (smem, wm, wn, l15, xq0, xq4, acc);
        else if (t % 3 == 1) gemm_step<12288>(smem, wm, wn, l15, xq0, xq4, acc);
        else                 gemm_step<24576>(smem, wm, wn, l15, xq0, xq4, acc);
        if (t + 2 < 8) {
            if      ((t + 2) % 3 == 0) ISSG(0);
            else if ((t + 2) % 3 == 1) ISSG(12288);
            else                       ISSG(24576);
        }
    }
#undef ISSG

    for (int mi = 0; mi < 4; mi++)
        for (int ni = 0; ni < 2; ni++)
            for (int r = 0; r < 4; r++) {
                int row = m0 + wm + mi * 16 + q * 4 + r;
                int col = n0 + wn + ni * 16 + l15;
                C[(long)row * Nd + col] = acc[mi][ni][r] + bias[col];
            }
}

// ---------------------------------------------------------------------------
// K2 compute bodies (unchanged R10). Template-const buffer bases.
// ---------------------------------------------------------------------------
template <int SB>
__device__ __forceinline__ void comp1(const unsigned short* smem, int a0, int a4,
                                      const bf16x8* lfq, float sc, float& rsl)
{
#pragma unroll
    for (int ns = 0; ns < 8; ns++) {
        f32x4 cv = {0.f, 0.f, 0.f, 0.f};
        cv = mfma16(ld_frag(&smem[SB + ns * 1024 + a0]), lfq[0], cv);
        cv = mfma16(ld_frag(&smem[SB + ns * 1024 + a4]), lfq[1], cv);
#pragma unroll
        for (int r = 0; r < 4; r++) rsl += fexp2(cv[r] * sc);
    }
}

template <int KB>
__device__ __forceinline__ void comp2(const unsigned short* smem, int a0, int a4,
                                      const bf16x8* qf, const bf16x8* lfq,
                                      float k0c, float k2c, float k1, float sc,
                                      float& rs, f32x4* o)
{
#pragma unroll
    for (int ns2 = 0; ns2 < 2; ns2++) {
        FragU32 fa;
#pragma unroll
        for (int h2 = 0; h2 < 2; h2++) {
            const int ns = ns2 * 2 + h2;
            f32x4 a = {0.f, 0.f, 0.f, 0.f};
            a = mfma16(ld_frag(&smem[KB + ns * 1024 + a0]), qf[0], a);
            a = mfma16(ld_frag(&smem[KB + ns * 1024 + a4]), qf[1], a);
            f32x4 cv = {0.f, 0.f, 0.f, 0.f};
            cv = mfma16(ld_frag(&smem[KB + 4096 + ns * 1024 + a0]), lfq[0], cv);
            cv = mfma16(ld_frag(&smem[KB + 4096 + ns * 1024 + a4]), lfq[1], cv);
            float pv[4];
#pragma unroll
            for (int r = 0; r < 4; r++) {
                float els = fexp2(cv[r] * sc);
                float t = fmaf(k0c, a[r], k2c);
                t = fmaf(k1, els, t);
                pv[r] = fexp2(t);
                rs += pv[r];
            }
            fa.u[h2 * 2 + 0] = pack_bf2(pv[1], pv[0]);
            fa.u[h2 * 2 + 1] = pack_bf2(pv[3], pv[2]);
        }
        const int av = ns2 ? a4 : a0;
#pragma unroll
        for (int dt = 0; dt < 4; dt++)
            o[dt] = mfma16(fa.b, ld_frag(&smem[KB + 8192 + dt * 1024 + av]), o[dt]);
    }
}

// ---------------------------------------------------------------------------
// K2: fused flash attention — R10 structure verbatim (best measured: 54.5us).
// ---------------------------------------------------------------------------
__global__ __launch_bounds__(512) void k_flash(
    const unsigned short* __restrict__ qkv_bf, const unsigned short* __restrict__ lid_bf,
    const unsigned short* __restrict__ vt,
    const unsigned short* __restrict__ wm_bf, const float* __restrict__ b_merge,
    const float* __restrict__ conv_w, const float* __restrict__ conv_b,
    unsigned short* __restrict__ tmp_bf)
{
    __shared__ unsigned short smem[36864];   // 72KB: sweep2 bufs at 0/12288/24576
    __shared__ float sRS[8][16];

    const int tid = threadIdx.x, lane = tid & 63, wave = tid >> 6;   // wave 0..7
    const int q = lane >> 4, l15 = lane & 15, l7 = l15 & 7;
    const int xq0 = (q ^ l7) << 3, xq4 = ((q + 4) ^ l7) << 3;
    const int a0 = l15 * 64 + xq0, a4 = l15 * 64 + xq4;
    const int bh = blockIdx.x, ipair = blockIdx.y;   // x=bh for XCD locality
    const int b = bh >> 3, h = bh & 7;
    const int i0w = ipair * 128 + wave * 16;
    const long rowB = (long)b * N_;
    const int colh = h * DH_;
    const float k0c = conv_w[0] * SCALE_ * LOG2E_;
    const float k2c = conv_b[0] * LOG2E_;
    const float c1L = conv_w[1] * LOG2E_;
    const float sc = SCALE_ * LOG2E_;

    // per-thread staging chunk base (16B per thread per 8KB sub-buffer)
    const int srow = tid >> 3;                                // 0..63
    const int sgc  = ((tid & 7) ^ (srow & 7)) << 3;
    unsigned short* sd = &smem[tid * 8];
    const unsigned short* gK = &qkv_bf[(rowB + srow) * 1536 + 512 + colh + sgc];
    const unsigned short* gL = &lid_bf[(rowB + srow) * INNER_ + colh + sgc];
    const unsigned short* gV = &vt[(long)(colh + srow) * (B_ * N_) + rowB + sgc];
    const unsigned short* gL1a = &lid_bf[(rowB + srow) * INNER_ + colh + sgc];
    const unsigned short* gL1b = &lid_bf[(rowB + 64 + srow) * INNER_ + colh + sgc];

    // Q / lid query fragments (B-operand: row i = l15, contiguous d)
    bf16x8 qf[2], lfq[2];
#pragma unroll
    for (int ks = 0; ks < 2; ks++) {
        qf[ks]  = ld_frag(&qkv_bf[(rowB + i0w + l15) * 1536 + colh + ks * 32 + q * 8]);
        lfq[ks] = ld_frag(&lid_bf[(rowB + i0w + l15) * INNER_ + colh + ks * 32 + q * 8]);
    }
    // force materialization so the compiler's waitcnt for these loads lands
    // HERE, not as a vmcnt(0) drain inside the pipelined loops
    KEEP8(qf[0]); KEEP8(qf[1]); KEEP8(lfq[0]); KEEP8(lfq[1]);
    WAITV(0);

    // ISS1(off): stage one 128-row lidar tile (16KB = 2 gl_lds) at ushort off
#define ISS1(off) do { gl_lds(gL1a, sd + (off)); gl_lds(gL1b, sd + (off) + 4096); \
                       gL1a += 128 * INNER_; gL1b += 128 * INNER_; } while (0)
    // ISS2(off): stage one 64-token K|L|V tile (24KB = 3 gl_lds) at ushort off
#define ISS2(off) do { gl_lds(gK, sd + (off)); gl_lds(gL, sd + (off) + 4096); \
                       gl_lds(gV, sd + (off) + 8192); \
                       gK += 64 * 1536; gL += 64 * INNER_; gV += 64; } while (0)

    // ---- sweep 1: lidar softmax denominator (8 tiles x 128 rows, 16KB each,
    //      3 buffers at ushort offsets 0 / 8192 / 16384; one barrier/tile) ----
    float rsl = 0.f;
    ISS1(0); ISS1(8192);                  // t0 -> buf0, t1 -> buf1
#pragma unroll
    for (int t = 0; t < 8; t++) {
        if (t < 7) { WAITV(2); } else { WAITV(0); }
        BARF();
        __builtin_amdgcn_s_setprio(1);
        if      (t % 3 == 0) comp1<0>    (smem, a0, a4, lfq, sc, rsl);
        else if (t % 3 == 1) comp1<8192> (smem, a0, a4, lfq, sc, rsl);
        else                 comp1<16384>(smem, a0, a4, lfq, sc, rsl);
        __builtin_amdgcn_s_setprio(0);
        if (t + 2 < 8) {
            if      ((t + 2) % 3 == 0) ISS1(0);
            else if ((t + 2) % 3 == 1) ISS1(8192);
            else                       ISS1(16384);
        }
    }

    // transition: all waves done reading sweep-1 buffers before sweep-2
    // staging overwrites the region
    BARF();
    ISS2(0); ISS2(12288);                 // t0 -> buf0, t1 -> buf1
    rsl += __shfl_xor(rsl, 16);           // reduce hides under the loads
    rsl += __shfl_xor(rsl, 32);
    const float k1 = c1L / rsl;
    float rs = 0.f;
    f32x4 o[4] = {};   // o[dt]: lane holds O[i = q*4+r][d = dt*16 + l15]

    // ---- sweep 2: blended flash (16 tiles x 64 tokens, 24KB each,
    //      3 buffers at ushort offsets 0 / 12288 / 24576; one barrier/tile) ----
#pragma unroll
    for (int t = 0; t < 16; t++) {
        if (t < 15) { WAITV(3); } else { WAITV(0); }
        BARF();
        __builtin_amdgcn_s_setprio(1);
        if      (t % 3 == 0) comp2<0>    (smem, a0, a4, qf, lfq, k0c, k2c, k1, sc, rs, o);
        else if (t % 3 == 1) comp2<12288>(smem, a0, a4, qf, lfq, k0c, k2c, k1, sc, rs, o);
        else                 comp2<24576>(smem, a0, a4, qf, lfq, k0c, k2c, k1, sc, rs, o);
        __builtin_amdgcn_s_setprio(0);
        if (t + 2 < 16) {
            if      ((t + 2) % 3 == 0) ISS2(0);
            else if ((t + 2) % 3 == 1) ISS2(12288);
            else                       ISS2(24576);
        }
    }
#undef ISS1
#undef ISS2
    BARF();   // all waves done reading tile buffers -> pO overlay safe

    // ---- epilogue: normalize + fused per-head merge ----
    rs += __shfl_xor(rs, 16);
    rs += __shfl_xor(rs, 32);
    if (q == 0) sRS[wave][l15] = rs;          // wave-private, in-order
    float invr[4];
    for (int r = 0; r < 4; r++) invr[r] = 1.f / sRS[wave][q * 4 + r];

    unsigned short* pO = &smem[wave * 16 * 72];
#pragma unroll
    for (int dt = 0; dt < 4; dt++)
        for (int r = 0; r < 4; r++)
            pO[(q * 4 + r) * 72 + dt * 16 + l15] = f2bf(o[dt][r] * invr[r]);

    f32x4 mo[4] = {};
#pragma unroll
    for (int ks = 0; ks < 2; ks++) {
        bf16x8 af = ld_frag(&pO[l15 * 72 + ks * 32 + q * 8]);
#pragma unroll
        for (int ns = 0; ns < 4; ns++) {
            bf16x8 wf = ld_frag(&wm_bf[(ns * 16 + l15) * 64 + ks * 32 + q * 8]);
            mo[ns] = mfma16(af, wf, mo[ns]);
        }
    }
#pragma unroll
    for (int ns = 0; ns < 4; ns++) {
        float bm = b_merge[ns * 16 + l15];
        for (int r = 0; r < 4; r++) {
            long row = rowB + i0w + q * 4 + r;
            tmp_bf[row * INNER_ + colh + ns * 16 + l15] = f2bf(mo[ns][r] + bm);
        }
    }
}

// ---------------------------------------------------------------------------
extern "C" void kernel_launch(void* const* d_in, const int* in_sizes, int n_in,
                              void* d_out, int out_size, void* d_ws, size_t ws_size,
                              hipStream_t stream) {
    const float* x       = (const float*)d_in[0];
    const float* lidar   = (const float*)d_in[1];
    const float* w_qkv   = (const float*)d_in[2];
    const float* w_merge = (const float*)d_in[3];
    const float* b_merge = (const float*)d_in[4];
    const float* w_out   = (const float*)d_in[5];
    const float* b_out   = (const float*)d_in[6];
    const float* conv_w  = (const float*)d_in[7];
    const float* conv_b  = (const float*)d_in[8];

    float* out0      = (float*)d_out;                      // [B,N,DIM]
    float* out_lidar = out0 + (long)B_ * N_ * INNER_;      // [B,N,INNER]

    size_t off = 0;
    auto carve = [&](size_t bytes) {
        void* p = (char*)d_ws + off;
        off += (bytes + 255) & ~(size_t)255;
        return p;
    };
    unsigned short* qkv_bf  = (unsigned short*)carve((size_t)B_ * N_ * 3 * INNER_ * 2);
    unsigned short* lid_bf  = (unsigned short*)carve((size_t)B_ * N_ * INNER_ * 2);
    unsigned short* x_bf    = (unsigned short*)carve((size_t)B_ * N_ * DIM_ * 2);
    unsigned short* wqkv_bf = (unsigned short*)carve((size_t)3 * INNER_ * DIM_ * 2);
    unsigned short* wout_bf = (unsigned short*)carve((size_t)DIM_ * INNER_ * 2);
    unsigned short* wm_bf   = (unsigned short*)carve((size_t)DH_ * DH_ * 2);
    unsigned short* tmp_bf  = (unsigned short*)carve((size_t)B_ * N_ * INNER_ * 2);
    unsigned short* vt_bf   = (unsigned short*)carve((size_t)INNER_ * B_ * N_ * 2);

    k_convert<<<2305, 256, 0, stream>>>(x, lidar, w_qkv, w_merge, w_out,
                                        x_bf, lid_bf, out_lidar,
                                        wqkv_bf, wm_bf, wout_bf);

    k_gemm_qkv<<<dim3(64, 24), 256, 0, stream>>>(
        x_bf, wqkv_bf, qkv_bf, vt_bf);

    k_flash<<<dim3(64, 8), 512, 0, stream>>>(
        qkv_bf, lid_bf, vt_bf, wm_bf, b_merge, conv_w, conv_b, tmp_bf);

    k_gemm_out<<<dim3(64, 8), 256, 0, stream>>>(
        tmp_bf, wout_bf, b_out, out0);
}

// Round 15
// 174.891 us; speedup vs baseline: 1.0417x; 1.0012x over previous
//
#include <hip/hip_runtime.h>
#include <hip/hip_bf16.h>

// Problem constants
#define B_      8
#define N_      1024
#define DIM_    512
#define H_      8
#define DH_     64
#define INNER_  512
#define SCALE_  0.125f
#define LOG2E_  1.4426950408889634f

typedef __attribute__((ext_vector_type(8))) __bf16         bf16x8;
typedef __attribute__((ext_vector_type(8))) unsigned short ushort8;
typedef __attribute__((ext_vector_type(4))) float          f32x4;

union FragCast { ushort8 u; bf16x8 b; };
union FragU32  { unsigned int u[4]; bf16x8 b; };

__device__ inline bf16x8 ld_frag(const unsigned short* p) {
    FragCast f; f.u = *(const ushort8*)p; return f.b;
}

__device__ inline f32x4 mfma16(bf16x8 a, bf16x8 b, f32x4 c) {
    return __builtin_amdgcn_mfma_f32_16x16x32_bf16(a, b, c, 0, 0, 0);
}

__device__ inline float fexp2(float x) { return __builtin_amdgcn_exp2f(x); }

// round-to-nearest-even float -> bf16 bits
__device__ inline unsigned short f2bf(float x) {
    unsigned int u = __float_as_uint(x);
    unsigned int lsb = (u >> 16) & 1u;
    u += 0x7fffu + lsb;
    return (unsigned short)(u >> 16);
}

// truncating pack: (bf16(hi) << 16) | bf16(lo), one v_perm
__device__ inline unsigned int pack_bf2(float hi, float lo) {
    return __builtin_amdgcn_perm(__float_as_uint(hi), __float_as_uint(lo), 0x07060302u);
}

// async global->LDS, 16 bytes per lane (m97 pattern)
__device__ inline void gl_lds(const unsigned short* g, unsigned short* l) {
    __builtin_amdgcn_global_load_lds(
        (const __attribute__((address_space(1))) unsigned int*)g,
        (__attribute__((address_space(3))) unsigned int*)l, 16, 0, 0);
}

// raw barrier with compile-time memory fences (keeps gl_lds/ds_read on their
// side of the barrier without emitting a vmcnt(0) drain like __syncthreads)
#define BARF() do { asm volatile("" ::: "memory"); \
                    __builtin_amdgcn_s_barrier();  \
                    asm volatile("" ::: "memory"); } while (0)
#define WAITV(n) asm volatile("s_waitcnt vmcnt(" #n ")" ::: "memory")

// keep a bf16x8 fragment live via 4 scalar u32 asm operands
#define KEEP8(x) do { FragU32 _k; _k.b = (x); \
    asm volatile("" :: "v"(_k.u[0]), "v"(_k.u[1]), "v"(_k.u[2]), "v"(_k.u[3])); } while (0)

// ---------------------------------------------------------------------------
// K0: fp32 -> bf16 conversions, block-uniform region dispatch (R10/R12).
// ---------------------------------------------------------------------------
__global__ __launch_bounds__(256) void k_convert(
    const float* __restrict__ x, const float* __restrict__ lidar,
    const float* __restrict__ wqkv, const float* __restrict__ wmerge,
    const float* __restrict__ wout,
    unsigned short* __restrict__ x_bf, unsigned short* __restrict__ lid_bf,
    float* __restrict__ out_lidar,
    unsigned short* __restrict__ wqkv_bf, unsigned short* __restrict__ wm_bf,
    unsigned short* __restrict__ wout_bf)
{
    const int bx = blockIdx.x, tid = threadIdx.x;
    const float* src; unsigned short* dst; bool isLid = false; long base;
    if (bx < 1024)      { src = x;      dst = x_bf;    base = (long)bx * 1024; }
    else if (bx < 2048) { src = lidar;  dst = lid_bf;  base = (long)(bx - 1024) * 1024; isLid = true; }
    else if (bx < 2240) { src = wqkv;   dst = wqkv_bf; base = (long)(bx - 2048) * 1024; }
    else if (bx < 2304) { src = wout;   dst = wout_bf; base = (long)(bx - 2240) * 1024; }
    else                { src = wmerge; dst = wm_bf;   base = 0; }
    for (int k = 0; k < 4; k++) {
        long j = base + k * 256 + tid;
        float4 v = ((const float4*)src)[j];
        ushort4 o;
        o.x = f2bf(v.x); o.y = f2bf(v.y); o.z = f2bf(v.z); o.w = f2bf(v.w);
        ((ushort4*)dst)[j] = o;
        if (isLid) ((float4*)out_lidar)[j] = v;
    }
}

// ---------------------------------------------------------------------------
// GEMM K-step for 8-wave 128x64 tile: acc[2][2] per wave, wm in {0,32,64,96},
// wn in {0,32}. A at KB (8192 ushorts), B at KB+8192. Template-const base.
// ---------------------------------------------------------------------------
template <int KB>
__device__ __forceinline__ void gemm_step8(const unsigned short* smem,
                                           int wm, int wn, int l15,
                                           int xq0, int xq4, f32x4 acc[2][2])
{
#pragma unroll
    for (int kk = 0; kk < 2; kk++) {
        const int xx = kk ? xq4 : xq0;
        bf16x8 af[2], bfr[2];
#pragma unroll
        for (int i = 0; i < 2; i++)
            af[i]  = ld_frag(&smem[KB + (wm + i * 16 + l15) * 64 + xx]);
#pragma unroll
        for (int i = 0; i < 2; i++)
            bfr[i] = ld_frag(&smem[KB + 8192 + (wn + i * 16 + l15) * 64 + xx]);
#pragma unroll
        for (int mi = 0; mi < 2; mi++)
#pragma unroll
            for (int ni = 0; ni < 2; ni++)
                acc[mi][ni] = mfma16(af[mi], bfr[ni], acc[mi][ni]);
    }
}

// ---------------------------------------------------------------------------
// K1: QKV GEMM, C = A * B^T, 128x64 tile, BK=64, K=512 (8 steps), 512 thr
// (8 waves -> 16 waves/CU at 2 blocks/CU, 2x the R12 occupancy).
// R10 schedule: 3-buffer LDS (3 x 24KB = 72KB), ONE barrier per K-step,
// counted vmcnt (WAITV(3) steady; drain at tail), issue t+2 after compute(t).
// ---------------------------------------------------------------------------
__global__ __launch_bounds__(512) void k_gemm_qkv(
    const unsigned short* __restrict__ A, const unsigned short* __restrict__ Bm,
    unsigned short* __restrict__ C, unsigned short* __restrict__ vt)
{
    __shared__ unsigned short smem[36864];   // 72KB: bufs at 0 / 12288 / 24576
    const int tid  = threadIdx.x;
    const int lane = tid & 63, wave = tid >> 6;
    const int q = lane >> 4, l15 = lane & 15, l7 = l15 & 7;
    const int xq0 = (q ^ l7) << 3, xq4 = ((q + 4) ^ l7) << 3;
    const int m0 = blockIdx.x * 128, n0 = blockIdx.y * 64;
    const int wm = (wave >> 1) * 32, wn = (wave & 1) * 32;
    const int K = DIM_, Nd = 3 * INNER_;
    f32x4 acc[2][2] = {};

    // per-thread staging: 3 x 16B chunks (A rows 0-63, A rows 64-127, B rows)
    const int r0  = tid >> 3;                               // 0..63
    const int gc  = ((tid & 7) ^ (r0 & 7)) << 3;
    const unsigned short* gA0 = &A [(long)(m0 + r0     ) * K + gc];
    const unsigned short* gA1 = &A [(long)(m0 + r0 + 64) * K + gc];
    const unsigned short* gB0 = &Bm[(long)(n0 + r0     ) * K + gc];
    unsigned short* sd = &smem[tid * 8];

#define ISSG(off) do { gl_lds(gA0, sd + (off)); gl_lds(gA1, sd + (off) + 4096); \
                       gl_lds(gB0, sd + (off) + 8192); \
                       gA0 += 64; gA1 += 64; gB0 += 64; } while (0)

    ISSG(0); ISSG(12288);                 // t0 -> buf0, t1 -> buf1
#pragma unroll
    for (int t = 0; t < 8; t++) {
        if (t < 7) { WAITV(3); } else { WAITV(0); }
        BARF();
        if      (t % 3 == 0) gemm_step8<0>    (smem, wm, wn, l15, xq0, xq4, acc);
        else if (t % 3 == 1) gemm_step8<12288>(smem, wm, wn, l15, xq0, xq4, acc);
        else                 gemm_step8<24576>(smem, wm, wn, l15, xq0, xq4, acc);
        if (t + 2 < 8) {
            if      ((t + 2) % 3 == 0) ISSG(0);
            else if ((t + 2) % 3 == 1) ISSG(12288);
            else                       ISSG(24576);
        }
    }
#undef ISSG

    if (n0 < 1024) {
        for (int mi = 0; mi < 2; mi++)
            for (int ni = 0; ni < 2; ni++)
                for (int r = 0; r < 4; r++) {
                    int row = m0 + wm + mi * 16 + q * 4 + r;
                    int col = n0 + wn + ni * 16 + l15;
                    C[(long)row * Nd + col] = f2bf(acc[mi][ni][r]);
                }
    } else {
        // ---- V epilogue: acc -> LDS sT[f][tok] (64 x 136) -> coalesced vt ----
        BARF();   // all waves done reading tile buffers
        for (int mi = 0; mi < 2; mi++) {
            int t0 = wm + mi * 16 + q * 4;
            for (int ni = 0; ni < 2; ni++) {
                int f = wn + ni * 16 + l15;
                ushort4 o4;
                o4.x = f2bf(acc[mi][ni][0]); o4.y = f2bf(acc[mi][ni][1]);
                o4.z = f2bf(acc[mi][ni][2]); o4.w = f2bf(acc[mi][ni][3]);
                *(ushort4*)&smem[f * 136 + t0] = o4;   // 8B store, 2-way alias = free
            }
        }
        BARF();
        const long fb = (long)(n0 - 1024) * (B_ * N_) + m0;
        for (int i = 0; i < 2; i++) {
            int g = i * 512 + tid;              // 64 f x 16 groups
            int f = g >> 4, grp = g & 15;
            int base = (grp >> 2) * 32 + (grp & 3) * 4;
            ushort4 a4 = *(const ushort4*)&smem[f * 136 + base];
            ushort4 b4 = *(const ushort4*)&smem[f * 136 + base + 16];
            ushort8 o8 = {a4.x, a4.y, a4.z, a4.w, b4.x, b4.y, b4.z, b4.w};
            *(ushort8*)&vt[fb + (long)f * (B_ * N_) + grp * 8] = o8;
        }
    }
}

// ---------------------------------------------------------------------------
// K3: out GEMM (fp32 out + bias), 128x64 tile, K=512, 512 thr — same schedule.
// ---------------------------------------------------------------------------
__global__ __launch_bounds__(512) void k_gemm_out(
    const unsigned short* __restrict__ A, const unsigned short* __restrict__ Bm,
    const float* __restrict__ bias, float* __restrict__ C)
{
    __shared__ unsigned short smem[36864];   // 72KB: bufs at 0 / 12288 / 24576
    const int tid  = threadIdx.x;
    const int lane = tid & 63, wave = tid >> 6;
    const int q = lane >> 4, l15 = lane & 15, l7 = l15 & 7;
    const int xq0 = (q ^ l7) << 3, xq4 = ((q + 4) ^ l7) << 3;
    const int m0 = blockIdx.x * 128, n0 = blockIdx.y * 64;
    const int wm = (wave >> 1) * 32, wn = (wave & 1) * 32;
    const int K = INNER_, Nd = DIM_;
    f32x4 acc[2][2] = {};

    const int r0  = tid >> 3;
    const int gc  = ((tid & 7) ^ (r0 & 7)) << 3;
    const unsigned short* gA0 = &A [(long)(m0 + r0     ) * K + gc];
    const unsigned short* gA1 = &A [(long)(m0 + r0 + 64) * K + gc];
    const unsigned short* gB0 = &Bm[(long)(n0 + r0     ) * K + gc];
    unsigned short* sd = &smem[tid * 8];

#define ISSG(off) do { gl_lds(gA0, sd + (off)); gl_lds(gA1, sd + (off) + 4096); \
                       gl_lds(gB0, sd + (off) + 8192); \
                       gA0 += 64; gA1 += 64; gB0 += 64; } while (0)

    ISSG(0); ISSG(12288);
#pragma unroll
    for (int t = 0; t < 8; t++) {
        if (t < 7) { WAITV(3); } else { WAITV(0); }
        BARF();
        if      (t % 3 == 0) gemm_step8<0>    (smem, wm, wn, l15, xq0, xq4, acc);
        else if (t % 3 == 1) gemm_step8<12288>(smem, wm, wn, l15, xq0, xq4, acc);
        else                 gemm_step8<24576>(smem, wm, wn, l15, xq0, xq4, acc);
        if (t + 2 < 8) {
            if      ((t + 2) % 3 == 0) ISSG(0);
            else if ((t + 2) % 3 == 1) ISSG(12288);
            else                       ISSG(24576);
        }
    }
#undef ISSG

    for (int mi = 0; mi < 2; mi++)
        for (int ni = 0; ni < 2; ni++)
            for (int r = 0; r < 4; r++) {
                int row = m0 + wm + mi * 16 + q * 4 + r;
                int col = n0 + wn + ni * 16 + l15;
                C[(long)row * Nd + col] = acc[mi][ni][r] + bias[col];
            }
}

// ---------------------------------------------------------------------------
// K2 compute bodies (unchanged R10). Template-const buffer bases.
// ---------------------------------------------------------------------------
template <int SB>
__device__ __forceinline__ void comp1(const unsigned short* smem, int a0, int a4,
                                      const bf16x8* lfq, float sc, float& rsl)
{
#pragma unroll
    for (int ns = 0; ns < 8; ns++) {
        f32x4 cv = {0.f, 0.f, 0.f, 0.f};
        cv = mfma16(ld_frag(&smem[SB + ns * 1024 + a0]), lfq[0], cv);
        cv = mfma16(ld_frag(&smem[SB + ns * 1024 + a4]), lfq[1], cv);
#pragma unroll
        for (int r = 0; r < 4; r++) rsl += fexp2(cv[r] * sc);
    }
}

template <int KB>
__device__ __forceinline__ void comp2(const unsigned short* smem, int a0, int a4,
                                      const bf16x8* qf, const bf16x8* lfq,
                                      float k0c, float k2c, float k1, float sc,
                                      float& rs, f32x4* o)
{
#pragma unroll
    for (int ns2 = 0; ns2 < 2; ns2++) {
        FragU32 fa;
#pragma unroll
        for (int h2 = 0; h2 < 2; h2++) {
            const int ns = ns2 * 2 + h2;
            f32x4 a = {0.f, 0.f, 0.f, 0.f};
            a = mfma16(ld_frag(&smem[KB + ns * 1024 + a0]), qf[0], a);
            a = mfma16(ld_frag(&smem[KB + ns * 1024 + a4]), qf[1], a);
            f32x4 cv = {0.f, 0.f, 0.f, 0.f};
            cv = mfma16(ld_frag(&smem[KB + 4096 + ns * 1024 + a0]), lfq[0], cv);
            cv = mfma16(ld_frag(&smem[KB + 4096 + ns * 1024 + a4]), lfq[1], cv);
            float pv[4];
#pragma unroll
            for (int r = 0; r < 4; r++) {
                float els = fexp2(cv[r] * sc);
                float t = fmaf(k0c, a[r], k2c);
                t = fmaf(k1, els, t);
                pv[r] = fexp2(t);
                rs += pv[r];
            }
            fa.u[h2 * 2 + 0] = pack_bf2(pv[1], pv[0]);
            fa.u[h2 * 2 + 1] = pack_bf2(pv[3], pv[2]);
        }
        const int av = ns2 ? a4 : a0;
#pragma unroll
        for (int dt = 0; dt < 4; dt++)
            o[dt] = mfma16(fa.b, ld_frag(&smem[KB + 8192 + dt * 1024 + av]), o[dt]);
    }
}

// ---------------------------------------------------------------------------
// K2: fused flash attention — R10 structure verbatim (best measured: 54.5us).
// ---------------------------------------------------------------------------
__global__ __launch_bounds__(512) void k_flash(
    const unsigned short* __restrict__ qkv_bf, const unsigned short* __restrict__ lid_bf,
    const unsigned short* __restrict__ vt,
    const unsigned short* __restrict__ wm_bf, const float* __restrict__ b_merge,
    const float* __restrict__ conv_w, const float* __restrict__ conv_b,
    unsigned short* __restrict__ tmp_bf)
{
    __shared__ unsigned short smem[36864];   // 72KB: sweep2 bufs at 0/12288/24576
    __shared__ float sRS[8][16];

    const int tid = threadIdx.x, lane = tid & 63, wave = tid >> 6;   // wave 0..7
    const int q = lane >> 4, l15 = lane & 15, l7 = l15 & 7;
    const int xq0 = (q ^ l7) << 3, xq4 = ((q + 4) ^ l7) << 3;
    const int a0 = l15 * 64 + xq0, a4 = l15 * 64 + xq4;
    const int bh = blockIdx.x, ipair = blockIdx.y;   // x=bh for XCD locality
    const int b = bh >> 3, h = bh & 7;
    const int i0w = ipair * 128 + wave * 16;
    const long rowB = (long)b * N_;
    const int colh = h * DH_;
    const float k0c = conv_w[0] * SCALE_ * LOG2E_;
    const float k2c = conv_b[0] * LOG2E_;
    const float c1L = conv_w[1] * LOG2E_;
    const float sc = SCALE_ * LOG2E_;

    // per-thread staging chunk base (16B per thread per 8KB sub-buffer)
    const int srow = tid >> 3;                                // 0..63
    const int sgc  = ((tid & 7) ^ (srow & 7)) << 3;
    unsigned short* sd = &smem[tid * 8];
    const unsigned short* gK = &qkv_bf[(rowB + srow) * 1536 + 512 + colh + sgc];
    const unsigned short* gL = &lid_bf[(rowB + srow) * INNER_ + colh + sgc];
    const unsigned short* gV = &vt[(long)(colh + srow) * (B_ * N_) + rowB + sgc];
    const unsigned short* gL1a = &lid_bf[(rowB + srow) * INNER_ + colh + sgc];
    const unsigned short* gL1b = &lid_bf[(rowB + 64 + srow) * INNER_ + colh + sgc];

    // Q / lid query fragments (B-operand: row i = l15, contiguous d)
    bf16x8 qf[2], lfq[2];
#pragma unroll
    for (int ks = 0; ks < 2; ks++) {
        qf[ks]  = ld_frag(&qkv_bf[(rowB + i0w + l15) * 1536 + colh + ks * 32 + q * 8]);
        lfq[ks] = ld_frag(&lid_bf[(rowB + i0w + l15) * INNER_ + colh + ks * 32 + q * 8]);
    }
    // force materialization so the compiler's waitcnt for these loads lands
    // HERE, not as a vmcnt(0) drain inside the pipelined loops
    KEEP8(qf[0]); KEEP8(qf[1]); KEEP8(lfq[0]); KEEP8(lfq[1]);
    WAITV(0);

    // ISS1(off): stage one 128-row lidar tile (16KB = 2 gl_lds) at ushort off
#define ISS1(off) do { gl_lds(gL1a, sd + (off)); gl_lds(gL1b, sd + (off) + 4096); \
                       gL1a += 128 * INNER_; gL1b += 128 * INNER_; } while (0)
    // ISS2(off): stage one 64-token K|L|V tile (24KB = 3 gl_lds) at ushort off
#define ISS2(off) do { gl_lds(gK, sd + (off)); gl_lds(gL, sd + (off) + 4096); \
                       gl_lds(gV, sd + (off) + 8192); \
                       gK += 64 * 1536; gL += 64 * INNER_; gV += 64; } while (0)

    // ---- sweep 1: lidar softmax denominator (8 tiles x 128 rows, 16KB each,
    //      3 buffers at ushort offsets 0 / 8192 / 16384; one barrier/tile) ----
    float rsl = 0.f;
    ISS1(0); ISS1(8192);                  // t0 -> buf0, t1 -> buf1
#pragma unroll
    for (int t = 0; t < 8; t++) {
        if (t < 7) { WAITV(2); } else { WAITV(0); }
        BARF();
        __builtin_amdgcn_s_setprio(1);
        if      (t % 3 == 0) comp1<0>    (smem, a0, a4, lfq, sc, rsl);
        else if (t % 3 == 1) comp1<8192> (smem, a0, a4, lfq, sc, rsl);
        else                 comp1<16384>(smem, a0, a4, lfq, sc, rsl);
        __builtin_amdgcn_s_setprio(0);
        if (t + 2 < 8) {
            if      ((t + 2) % 3 == 0) ISS1(0);
            else if ((t + 2) % 3 == 1) ISS1(8192);
            else                       ISS1(16384);
        }
    }

    // transition: all waves done reading sweep-1 buffers before sweep-2
    // staging overwrites the region
    BARF();
    ISS2(0); ISS2(12288);                 // t0 -> buf0, t1 -> buf1
    rsl += __shfl_xor(rsl, 16);           // reduce hides under the loads
    rsl += __shfl_xor(rsl, 32);
    const float k1 = c1L / rsl;
    float rs = 0.f;
    f32x4 o[4] = {};   // o[dt]: lane holds O[i = q*4+r][d = dt*16 + l15]

    // ---- sweep 2: blended flash (16 tiles x 64 tokens, 24KB each,
    //      3 buffers at ushort offsets 0 / 12288 / 24576; one barrier/tile) ----
#pragma unroll
    for (int t = 0; t < 16; t++) {
        if (t < 15) { WAITV(3); } else { WAITV(0); }
        BARF();
        __builtin_amdgcn_s_setprio(1);
        if      (t % 3 == 0) comp2<0>    (smem, a0, a4, qf, lfq, k0c, k2c, k1, sc, rs, o);
        else if (t % 3 == 1) comp2<12288>(smem, a0, a4, qf, lfq, k0c, k2c, k1, sc, rs, o);
        else                 comp2<24576>(smem, a0, a4, qf, lfq, k0c, k2c, k1, sc, rs, o);
        __builtin_amdgcn_s_setprio(0);
        if (t + 2 < 16) {
            if      ((t + 2) % 3 == 0) ISS2(0);
            else if ((t + 2) % 3 == 1) ISS2(12288);
            else                       ISS2(24576);
        }
    }
#undef ISS1
#undef ISS2
    BARF();   // all waves done reading tile buffers -> pO overlay safe

    // ---- epilogue: normalize + fused per-head merge ----
    rs += __shfl_xor(rs, 16);
    rs += __shfl_xor(rs, 32);
    if (q == 0) sRS[wave][l15] = rs;          // wave-private, in-order
    float invr[4];
    for (int r = 0; r < 4; r++) invr[r] = 1.f / sRS[wave][q * 4 + r];

    unsigned short* pO = &smem[wave * 16 * 72];
#pragma unroll
    for (int dt = 0; dt < 4; dt++)
        for (int r = 0; r < 4; r++)
            pO[(q * 4 + r) * 72 + dt * 16 + l15] = f2bf(o[dt][r] * invr[r]);

    f32x4 mo[4] = {};
#pragma unroll
    for (int ks = 0; ks < 2; ks++) {
        bf16x8 af = ld_frag(&pO[l15 * 72 + ks * 32 + q * 8]);
#pragma unroll
        for (int ns = 0; ns < 4; ns++) {
            bf16x8 wf = ld_frag(&wm_bf[(ns * 16 + l15) * 64 + ks * 32 + q * 8]);
            mo[ns] = mfma16(af, wf, mo[ns]);
        }
    }
#pragma unroll
    for (int ns = 0; ns < 4; ns++) {
        float bm = b_merge[ns * 16 + l15];
        for (int r = 0; r < 4; r++) {
            long row = rowB + i0w + q * 4 + r;
            tmp_bf[row * INNER_ + colh + ns * 16 + l15] = f2bf(mo[ns][r] + bm);
        }
    }
}

// ---------------------------------------------------------------------------
extern "C" void kernel_launch(void* const* d_in, const int* in_sizes, int n_in,
                              void* d_out, int out_size, void* d_ws, size_t ws_size,
                              hipStream_t stream) {
    const float* x       = (const float*)d_in[0];
    const float* lidar   = (const float*)d_in[1];
    const float* w_qkv   = (const float*)d_in[2];
    const float* w_merge = (const float*)d_in[3];
    const float* b_merge = (const float*)d_in[4];
    const float* w_out   = (const float*)d_in[5];
    const float* b_out   = (const float*)d_in[6];
    const float* conv_w  = (const float*)d_in[7];
    const float* conv_b  = (const float*)d_in[8];

    float* out0      = (float*)d_out;                      // [B,N,DIM]
    float* out_lidar = out0 + (long)B_ * N_ * INNER_;      // [B,N,INNER]

    size_t off = 0;
    auto carve = [&](size_t bytes) {
        void* p = (char*)d_ws + off;
        off += (bytes + 255) & ~(size_t)255;
        return p;
    };
    unsigned short* qkv_bf  = (unsigned short*)carve((size_t)B_ * N_ * 3 * INNER_ * 2);
    unsigned short* lid_bf  = (unsigned short*)carve((size_t)B_ * N_ * INNER_ * 2);
    unsigned short* x_bf    = (unsigned short*)carve((size_t)B_ * N_ * DIM_ * 2);
    unsigned short* wqkv_bf = (unsigned short*)carve((size_t)3 * INNER_ * DIM_ * 2);
    unsigned short* wout_bf = (unsigned short*)carve((size_t)DIM_ * INNER_ * 2);
    unsigned short* wm_bf   = (unsigned short*)carve((size_t)DH_ * DH_ * 2);
    unsigned short* tmp_bf  = (unsigned short*)carve((size_t)B_ * N_ * INNER_ * 2);
    unsigned short* vt_bf   = (unsigned short*)carve((size_t)INNER_ * B_ * N_ * 2);

    k_convert<<<2305, 256, 0, stream>>>(x, lidar, w_qkv, w_merge, w_out,
                                        x_bf, lid_bf, out_lidar,
                                        wqkv_bf, wm_bf, wout_bf);

    k_gemm_qkv<<<dim3(64, 24), 512, 0, stream>>>(
        x_bf, wqkv_bf, qkv_bf, vt_bf);

    k_flash<<<dim3(64, 8), 512, 0, stream>>>(
        qkv_bf, lid_bf, vt_bf, wm_bf, b_merge, conv_w, conv_b, tmp_bf);

    k_gemm_out<<<dim3(64, 8), 512, 0, stream>>>(
        tmp_bf, wout_bf, b_out, out0);
}